// Round 2
// baseline (1063.527 us; speedup 1.0000x reference)
//
#include <hip/hip_runtime.h>
#include <hip/hip_bf16.h>
#include <math.h>

#define NEG_SLOPE 0.2f

// ---------------- K1: xw1 = x @ W1, al1_src/al1_dst ----------------
// block = 256 threads = 4 waves; each wave computes one row (64 outputs)
__global__ __launch_bounds__(256) void k_feat1(
    const float* __restrict__ x, const float* __restrict__ W1,
    const float* __restrict__ a_src, const float* __restrict__ a_dst,
    float* __restrict__ xw, float* __restrict__ als, float* __restrict__ ald,
    int N)
{
    __shared__ float Wl[128 * 64];   // 32 KB
    __shared__ float xr[4][128];     // 2 KB
    int t = threadIdx.x;
    for (int i = t; i < 128 * 64; i += 256) Wl[i] = W1[i];
    __syncthreads();
    int wave = t >> 6, lane = t & 63;
    int row = blockIdx.x * 4 + wave;
    if (row >= N) return;
    xr[wave][lane]      = x[row * 128 + lane];
    xr[wave][64 + lane] = x[row * 128 + 64 + lane];
    float acc = 0.f;
#pragma unroll 8
    for (int k = 0; k < 128; ++k)
        acc = fmaf(xr[wave][k], Wl[k * 64 + lane], acc);
    xw[row * 64 + lane] = acc;
    int h = lane >> 4;
    float ps = acc * a_src[lane];  // a_src flat [4][16] == [lane]
    float pd = acc * a_dst[lane];
#pragma unroll
    for (int off = 1; off < 16; off <<= 1) {
        ps += __shfl_xor(ps, off, 64);
        pd += __shfl_xor(pd, off, 64);
    }
    if ((lane & 15) == 0) { als[row * 4 + h] = ps; ald[row * 4 + h] = pd; }
}

// ---------------- CSR build ----------------
__global__ __launch_bounds__(256) void k_fill_deg(int* deg, int N) {
    int i = blockIdx.x * 256 + threadIdx.x;
    if (i < N) deg[i] = 1;  // self-loop
}

__global__ __launch_bounds__(256) void k_deg(const int* __restrict__ dst, int* deg, int E) {
    int i = blockIdx.x * 256 + threadIdx.x;
    if (i < E) atomicAdd(&deg[dst[i]], 1);
}

// single-block exclusive scan over N=100k (1024 threads, ~98 elems each)
__global__ __launch_bounds__(1024) void k_scan(const int* __restrict__ deg, int* __restrict__ offs, int N) {
    __shared__ int ts[1024];
    int t = threadIdx.x;
    int per = (N + 1023) >> 10;
    int base = t * per;
    int s = 0;
    for (int i = 0; i < per; ++i) { int idx = base + i; if (idx < N) s += deg[idx]; }
    ts[t] = s;
    __syncthreads();
    for (int off = 1; off < 1024; off <<= 1) {
        int v = (t >= off) ? ts[t - off] : 0;
        __syncthreads();
        ts[t] += v;
        __syncthreads();
    }
    int run = ts[t] - s;  // exclusive prefix of this thread's chunk
    for (int i = 0; i < per; ++i) {
        int idx = base + i;
        if (idx < N) { offs[idx] = run; run += deg[idx]; }
    }
    if (t == 1023) offs[N] = run;
}

__global__ __launch_bounds__(256) void k_prep(const int* __restrict__ offs, int* cursor, int* ssrc, int N) {
    int i = blockIdx.x * 256 + threadIdx.x;
    if (i < N) { int o = offs[i]; cursor[i] = o + 1; ssrc[o] = i; }  // self-loop first
}

__global__ __launch_bounds__(256) void k_scatter(const int* __restrict__ src, const int* __restrict__ dst,
                                                 int* cursor, int* ssrc, int E) {
    int i = blockIdx.x * 256 + threadIdx.x;
    if (i < E) { int pos = atomicAdd(&cursor[dst[i]], 1); ssrc[pos] = src[i]; }
}

// ---------------- K2: layer-1 aggregate -> elu -> @W2 -> al2 ----------------
__global__ __launch_bounds__(256) void k_layer1(
    const int* __restrict__ offs, const int* __restrict__ ssrc,
    const float* __restrict__ xw, const float* __restrict__ alsrc, const float* __restrict__ aldst,
    const float* __restrict__ b1, const float* __restrict__ W2,
    const float* __restrict__ a2s, const float* __restrict__ a2d,
    float* __restrict__ xw2, float* __restrict__ al2s, float* __restrict__ al2d, int N)
{
    __shared__ float Wl[64 * 64];   // 16 KB
    __shared__ float hrow[4][64];
    int t = threadIdx.x;
    for (int i = t; i < 64 * 64; i += 256) Wl[i] = W2[i];
    __syncthreads();
    int wave = t >> 6, lane = t & 63;
    int n = blockIdx.x * 4 + wave;
    if (n >= N) return;
    int h = lane >> 4;
    int s0 = offs[n], s1 = offs[n + 1];
    float ad = aldst[n * 4 + h];
    float m = -1e30f;
    for (int i = s0; i < s1; ++i) {
        int s = ssrc[i];
        float e = alsrc[s * 4 + h] + ad;
        e = e > 0.f ? e : NEG_SLOPE * e;
        m = fmaxf(m, e);
    }
    float ssum = 0.f, acc = 0.f;
    for (int i = s0; i < s1; ++i) {
        int s = ssrc[i];
        float e = alsrc[s * 4 + h] + ad;
        e = e > 0.f ? e : NEG_SLOPE * e;
        float w = __expf(e - m);
        ssum += w;
        acc = fmaf(w, xw[s * 64 + lane], acc);
    }
    float hv = acc / (ssum + 1e-16f) + b1[lane];
    hv = hv > 0.f ? hv : expm1f(hv);     // elu
    hrow[wave][lane] = hv;
    float o = 0.f;
#pragma unroll 8
    for (int c = 0; c < 64; ++c)
        o = fmaf(hrow[wave][c], Wl[c * 64 + lane], o);
    xw2[n * 64 + lane] = o;
    float ps = o * a2s[lane];
    float pd = o * a2d[lane];
#pragma unroll
    for (int off = 1; off < 16; off <<= 1) {
        ps += __shfl_xor(ps, off, 64);
        pd += __shfl_xor(pd, off, 64);
    }
    if ((lane & 15) == 0) { al2s[n * 4 + h] = ps; al2d[n * 4 + h] = pd; }
}

// ---------------- K3: layer-2 aggregate -> elu -> @Wp + bp ----------------
__global__ __launch_bounds__(256) void k_layer2(
    const int* __restrict__ offs, const int* __restrict__ ssrc,
    const float* __restrict__ xw, const float* __restrict__ alsrc, const float* __restrict__ aldst,
    const float* __restrict__ b2v, const float* __restrict__ Wp, const float* __restrict__ bp,
    float* __restrict__ out, int N)
{
    __shared__ float Wl[64 * 64];
    __shared__ float hrow[4][64];
    int t = threadIdx.x;
    for (int i = t; i < 64 * 64; i += 256) Wl[i] = Wp[i];
    __syncthreads();
    int wave = t >> 6, lane = t & 63;
    int n = blockIdx.x * 4 + wave;
    if (n >= N) return;
    int h = lane >> 4;
    int s0 = offs[n], s1 = offs[n + 1];
    float ad = aldst[n * 4 + h];
    float m = -1e30f;
    for (int i = s0; i < s1; ++i) {
        int s = ssrc[i];
        float e = alsrc[s * 4 + h] + ad;
        e = e > 0.f ? e : NEG_SLOPE * e;
        m = fmaxf(m, e);
    }
    float ssum = 0.f, acc = 0.f;
    for (int i = s0; i < s1; ++i) {
        int s = ssrc[i];
        float e = alsrc[s * 4 + h] + ad;
        e = e > 0.f ? e : NEG_SLOPE * e;
        float w = __expf(e - m);
        ssum += w;
        acc = fmaf(w, xw[s * 64 + lane], acc);
    }
    float g = acc / (ssum + 1e-16f) + b2v[lane];
    g = g > 0.f ? g : expm1f(g);         // elu
    hrow[wave][lane] = g;
    float o = 0.f;
#pragma unroll 8
    for (int c = 0; c < 64; ++c)
        o = fmaf(hrow[wave][c], Wl[c * 64 + lane], o);
    o += bp[lane];
    out[n * 64 + lane] = o;
}

// ---------------- launch ----------------
extern "C" void kernel_launch(void* const* d_in, const int* in_sizes, int n_in,
                              void* d_out, int out_size, void* d_ws, size_t ws_size,
                              hipStream_t stream) {
    const float* x   = (const float*)d_in[0];
    const int*   ei  = (const int*)d_in[1];
    const float* W1  = (const float*)d_in[2];
    const float* a1s = (const float*)d_in[3];
    const float* a1d = (const float*)d_in[4];
    const float* b1  = (const float*)d_in[5];
    const float* W2  = (const float*)d_in[6];
    const float* a2s = (const float*)d_in[7];
    const float* a2d = (const float*)d_in[8];
    const float* b2  = (const float*)d_in[9];
    const float* Wp  = (const float*)d_in[10];
    const float* bp  = (const float*)d_in[11];
    float* out = (float*)d_out;

    const int N = in_sizes[0] / 128;
    const int E = in_sizes[1] / 2;
    const int Etot = E + N;
    const int* esrc = ei;
    const int* edst = ei + E;

    // workspace layout (~66 MB total)
    char* p = (char*)d_ws;
    auto alloc = [&](size_t bytes) {
        char* r = p;
        p += (bytes + 255) & ~(size_t)255;
        return (void*)r;
    };
    float* xw1   = (float*)alloc((size_t)N * 64 * 4);
    float* xw2   = (float*)alloc((size_t)N * 64 * 4);
    float* al1sv = (float*)alloc((size_t)N * 4 * 4);
    float* al1dv = (float*)alloc((size_t)N * 4 * 4);
    float* al2sv = (float*)alloc((size_t)N * 4 * 4);
    float* al2dv = (float*)alloc((size_t)N * 4 * 4);
    int*   deg   = (int*)alloc((size_t)N * 4);
    int*   offs  = (int*)alloc((size_t)(N + 1) * 4);
    int*   cur   = (int*)alloc((size_t)N * 4);
    int*   ssrc  = (int*)alloc((size_t)Etot * 4);
    (void)ws_size; (void)n_in; (void)out_size;

    dim3 blk(256);
    int gN256 = (N + 255) / 256;
    int gE256 = (E + 255) / 256;
    int gN4   = (N + 3) / 4;

    k_feat1<<<gN4, blk, 0, stream>>>(x, W1, a1s, a1d, xw1, al1sv, al1dv, N);
    k_fill_deg<<<gN256, blk, 0, stream>>>(deg, N);
    k_deg<<<gE256, blk, 0, stream>>>(edst, deg, E);
    k_scan<<<1, 1024, 0, stream>>>(deg, offs, N);
    k_prep<<<gN256, blk, 0, stream>>>(offs, cur, ssrc, N);
    k_scatter<<<gE256, blk, 0, stream>>>(esrc, edst, cur, ssrc, E);
    k_layer1<<<gN4, blk, 0, stream>>>(offs, ssrc, xw1, al1sv, al1dv,
                                      b1, W2, a2s, a2d, xw2, al2sv, al2dv, N);
    k_layer2<<<gN4, blk, 0, stream>>>(offs, ssrc, xw2, al2sv, al2dv,
                                      b2, Wp, bp, out, N);
}

// Round 3
// 1000.523 us; speedup vs baseline: 1.0630x; 1.0630x over previous
//
#include <hip/hip_runtime.h>
#include <hip/hip_bf16.h>
#include <math.h>

#define NEG_SLOPE 0.2f

typedef __hip_bfloat16 bf16;

// ---------------- K1: xw1 = x @ W1 (bf16 out), al1_src/al1_dst ----------------
// block = 256 = 4 waves; each wave computes 4 rows -> 16 rows/block (amortize W1 staging)
__global__ __launch_bounds__(256) void k_feat1(
    const float* __restrict__ x, const float* __restrict__ W1,
    const float* __restrict__ a_src, const float* __restrict__ a_dst,
    bf16* __restrict__ xwb, float* __restrict__ als, float* __restrict__ ald,
    int N)
{
    __shared__ float Wl[128 * 64];   // 32 KB
    int t = threadIdx.x;
    for (int i = t; i < 128 * 64; i += 256) Wl[i] = W1[i];
    __syncthreads();
    int wave = t >> 6, lane = t & 63;
    float as_l = a_src[lane];   // a_src flat [4][16] == [lane]
    float ad_l = a_dst[lane];
    int h = lane >> 4;
    int base = blockIdx.x * 16 + wave * 4;
    for (int r = 0; r < 4; ++r) {
        int row = base + r;
        if (row >= N) return;            // wave-uniform
        float x0 = x[row * 128 + lane];
        float x1 = x[row * 128 + 64 + lane];
        float acc = 0.f;
#pragma unroll
        for (int k = 0; k < 64; ++k)
            acc = fmaf(__shfl(x0, k, 64), Wl[k * 64 + lane], acc);
#pragma unroll
        for (int k = 0; k < 64; ++k)
            acc = fmaf(__shfl(x1, k, 64), Wl[(64 + k) * 64 + lane], acc);
        xwb[row * 64 + lane] = __float2bfloat16(acc);
        float ps = acc * as_l, pd = acc * ad_l;
#pragma unroll
        for (int off = 1; off < 16; off <<= 1) {
            ps += __shfl_xor(ps, off, 64);
            pd += __shfl_xor(pd, off, 64);
        }
        if ((lane & 15) == 0) { als[row * 4 + h] = ps; ald[row * 4 + h] = pd; }
    }
}

// ---------------- CSR build ----------------
__global__ __launch_bounds__(256) void k_fill_deg(int* deg, int N) {
    int i = blockIdx.x * 256 + threadIdx.x;
    if (i < N) deg[i] = 1;  // self-loop
}

__global__ __launch_bounds__(256) void k_deg(const int* __restrict__ dst, int* deg, int E) {
    int i = blockIdx.x * 256 + threadIdx.x;
    if (i < E) atomicAdd(&deg[dst[i]], 1);
}

// single-block exclusive scan over N=100k; also does k_prep's job (cursor + self-loop entry)
__global__ __launch_bounds__(1024) void k_scan(const int* __restrict__ deg, int* __restrict__ offs,
                                               int* __restrict__ cursor, int* __restrict__ ssrc, int N) {
    __shared__ int ts[1024];
    int t = threadIdx.x;
    int per = (N + 1023) >> 10;
    int base = t * per;
    int s = 0;
    for (int i = 0; i < per; ++i) { int idx = base + i; if (idx < N) s += deg[idx]; }
    ts[t] = s;
    __syncthreads();
    for (int off = 1; off < 1024; off <<= 1) {
        int v = (t >= off) ? ts[t - off] : 0;
        __syncthreads();
        ts[t] += v;
        __syncthreads();
    }
    int run = ts[t] - s;  // exclusive prefix of this thread's chunk
    for (int i = 0; i < per; ++i) {
        int idx = base + i;
        if (idx < N) {
            offs[idx] = run;
            cursor[idx] = run + 1;   // slot 0 = self-loop
            ssrc[run] = idx;
            run += deg[idx];
        }
    }
    if (t == 1023) offs[N] = run;
}

__global__ __launch_bounds__(256) void k_scatter(const int* __restrict__ src, const int* __restrict__ dst,
                                                 int* cursor, int* ssrc, int E) {
    int i = blockIdx.x * 256 + threadIdx.x;
    if (i < E) { int pos = atomicAdd(&cursor[dst[i]], 1); ssrc[pos] = src[i]; }
}

// ---------------- K2: layer-1 aggregate (single-pass softmax) -> elu -> @W2 -> al2 ----------------
__global__ __launch_bounds__(256) void k_layer1(
    const int* __restrict__ offs, const int* __restrict__ ssrc,
    const bf16* __restrict__ xwb, const float* __restrict__ alsrc, const float* __restrict__ aldst,
    const float* __restrict__ b1, const float* __restrict__ W2,
    const float* __restrict__ a2s, const float* __restrict__ a2d,
    bf16* __restrict__ xw2b, float* __restrict__ al2s, float* __restrict__ al2d, int N)
{
    __shared__ float Wl[64 * 64];   // 16 KB
    int t = threadIdx.x;
    for (int i = t; i < 64 * 64; i += 256) Wl[i] = W2[i];
    __syncthreads();
    int wave = t >> 6, lane = t & 63;
    int n = blockIdx.x * 4 + wave;
    if (n >= N) return;
    int h = lane >> 4;
    int s0 = offs[n], s1 = offs[n + 1];
    float ad = aldst[n * 4 + h];
    float ssum = 0.f, acc = 0.f;
    int i = s0;
    for (; i + 4 <= s1; i += 4) {
        int sa = ssrc[i], sb = ssrc[i + 1], sc = ssrc[i + 2], sd = ssrc[i + 3];
        float ea = alsrc[sa * 4 + h] + ad;
        float eb = alsrc[sb * 4 + h] + ad;
        float ec = alsrc[sc * 4 + h] + ad;
        float ed = alsrc[sd * 4 + h] + ad;
        float va = __bfloat162float(xwb[sa * 64 + lane]);
        float vb = __bfloat162float(xwb[sb * 64 + lane]);
        float vc = __bfloat162float(xwb[sc * 64 + lane]);
        float vd = __bfloat162float(xwb[sd * 64 + lane]);
        ea = ea > 0.f ? ea : NEG_SLOPE * ea;
        eb = eb > 0.f ? eb : NEG_SLOPE * eb;
        ec = ec > 0.f ? ec : NEG_SLOPE * ec;
        ed = ed > 0.f ? ed : NEG_SLOPE * ed;
        float wa = __expf(fminf(ea, 60.f));
        float wb = __expf(fminf(eb, 60.f));
        float wc = __expf(fminf(ec, 60.f));
        float wd = __expf(fminf(ed, 60.f));
        ssum += (wa + wb) + (wc + wd);
        acc = fmaf(wa, va, acc);
        acc = fmaf(wb, vb, acc);
        acc = fmaf(wc, vc, acc);
        acc = fmaf(wd, vd, acc);
    }
    for (; i < s1; ++i) {
        int s = ssrc[i];
        float e = alsrc[s * 4 + h] + ad;
        float v = __bfloat162float(xwb[s * 64 + lane]);
        e = e > 0.f ? e : NEG_SLOPE * e;
        float w = __expf(fminf(e, 60.f));
        ssum += w;
        acc = fmaf(w, v, acc);
    }
    float hv = acc / ssum + b1[lane];
    hv = hv > 0.f ? hv : expm1f(hv);     // elu
    float o = 0.f;
#pragma unroll 8
    for (int c = 0; c < 64; ++c)
        o = fmaf(__shfl(hv, c, 64), Wl[c * 64 + lane], o);
    xw2b[n * 64 + lane] = __float2bfloat16(o);
    float ps = o * a2s[lane], pd = o * a2d[lane];
#pragma unroll
    for (int off = 1; off < 16; off <<= 1) {
        ps += __shfl_xor(ps, off, 64);
        pd += __shfl_xor(pd, off, 64);
    }
    if ((lane & 15) == 0) { al2s[n * 4 + h] = ps; al2d[n * 4 + h] = pd; }
}

// ---------------- K3: layer-2 aggregate (single-pass) -> elu -> @Wp + bp ----------------
__global__ __launch_bounds__(256) void k_layer2(
    const int* __restrict__ offs, const int* __restrict__ ssrc,
    const bf16* __restrict__ xwb, const float* __restrict__ alsrc, const float* __restrict__ aldst,
    const float* __restrict__ b2v, const float* __restrict__ Wp, const float* __restrict__ bp,
    float* __restrict__ out, int N)
{
    __shared__ float Wl[64 * 64];
    int t = threadIdx.x;
    for (int i = t; i < 64 * 64; i += 256) Wl[i] = Wp[i];
    __syncthreads();
    int wave = t >> 6, lane = t & 63;
    int n = blockIdx.x * 4 + wave;
    if (n >= N) return;
    int h = lane >> 4;
    int s0 = offs[n], s1 = offs[n + 1];
    float ad = aldst[n * 4 + h];
    float ssum = 0.f, acc = 0.f;
    int i = s0;
    for (; i + 4 <= s1; i += 4) {
        int sa = ssrc[i], sb = ssrc[i + 1], sc = ssrc[i + 2], sd = ssrc[i + 3];
        float ea = alsrc[sa * 4 + h] + ad;
        float eb = alsrc[sb * 4 + h] + ad;
        float ec = alsrc[sc * 4 + h] + ad;
        float ed = alsrc[sd * 4 + h] + ad;
        float va = __bfloat162float(xwb[sa * 64 + lane]);
        float vb = __bfloat162float(xwb[sb * 64 + lane]);
        float vc = __bfloat162float(xwb[sc * 64 + lane]);
        float vd = __bfloat162float(xwb[sd * 64 + lane]);
        ea = ea > 0.f ? ea : NEG_SLOPE * ea;
        eb = eb > 0.f ? eb : NEG_SLOPE * eb;
        ec = ec > 0.f ? ec : NEG_SLOPE * ec;
        ed = ed > 0.f ? ed : NEG_SLOPE * ed;
        float wa = __expf(fminf(ea, 60.f));
        float wb = __expf(fminf(eb, 60.f));
        float wc = __expf(fminf(ec, 60.f));
        float wd = __expf(fminf(ed, 60.f));
        ssum += (wa + wb) + (wc + wd);
        acc = fmaf(wa, va, acc);
        acc = fmaf(wb, vb, acc);
        acc = fmaf(wc, vc, acc);
        acc = fmaf(wd, vd, acc);
    }
    for (; i < s1; ++i) {
        int s = ssrc[i];
        float e = alsrc[s * 4 + h] + ad;
        float v = __bfloat162float(xwb[s * 64 + lane]);
        e = e > 0.f ? e : NEG_SLOPE * e;
        float w = __expf(fminf(e, 60.f));
        ssum += w;
        acc = fmaf(w, v, acc);
    }
    float g = acc / ssum + b2v[lane];
    g = g > 0.f ? g : expm1f(g);         // elu
    float o = 0.f;
#pragma unroll 8
    for (int c = 0; c < 64; ++c)
        o = fmaf(__shfl(g, c, 64), Wl[c * 64 + lane], o);
    o += bp[lane];
    out[n * 64 + lane] = o;
}

// ---------------- launch ----------------
extern "C" void kernel_launch(void* const* d_in, const int* in_sizes, int n_in,
                              void* d_out, int out_size, void* d_ws, size_t ws_size,
                              hipStream_t stream) {
    const float* x   = (const float*)d_in[0];
    const int*   ei  = (const int*)d_in[1];
    const float* W1  = (const float*)d_in[2];
    const float* a1s = (const float*)d_in[3];
    const float* a1d = (const float*)d_in[4];
    const float* b1  = (const float*)d_in[5];
    const float* W2  = (const float*)d_in[6];
    const float* a2s = (const float*)d_in[7];
    const float* a2d = (const float*)d_in[8];
    const float* b2  = (const float*)d_in[9];
    const float* Wp  = (const float*)d_in[10];
    const float* bp  = (const float*)d_in[11];
    float* out = (float*)d_out;

    const int N = in_sizes[0] / 128;
    const int E = in_sizes[1] / 2;
    const int Etot = E + N;
    const int* esrc = ei;
    const int* edst = ei + E;

    // workspace layout (~42 MB)
    char* p = (char*)d_ws;
    auto alloc = [&](size_t bytes) {
        char* r = p;
        p += (bytes + 255) & ~(size_t)255;
        return (void*)r;
    };
    bf16*  xw1b  = (bf16*)alloc((size_t)N * 64 * 2);
    bf16*  xw2b  = (bf16*)alloc((size_t)N * 64 * 2);
    float* al1sv = (float*)alloc((size_t)N * 4 * 4);
    float* al1dv = (float*)alloc((size_t)N * 4 * 4);
    float* al2sv = (float*)alloc((size_t)N * 4 * 4);
    float* al2dv = (float*)alloc((size_t)N * 4 * 4);
    int*   deg   = (int*)alloc((size_t)N * 4);
    int*   offs  = (int*)alloc((size_t)(N + 1) * 4);
    int*   cur   = (int*)alloc((size_t)N * 4);
    int*   ssrc  = (int*)alloc((size_t)Etot * 4);
    (void)ws_size; (void)n_in; (void)out_size;

    dim3 blk(256);
    int gN256 = (N + 255) / 256;
    int gE256 = (E + 255) / 256;
    int gN4   = (N + 3) / 4;
    int gN16  = (N + 15) / 16;

    k_feat1<<<gN16, blk, 0, stream>>>(x, W1, a1s, a1d, xw1b, al1sv, al1dv, N);
    k_fill_deg<<<gN256, blk, 0, stream>>>(deg, N);
    k_deg<<<gE256, blk, 0, stream>>>(edst, deg, E);
    k_scan<<<1, 1024, 0, stream>>>(deg, offs, cur, ssrc, N);
    k_scatter<<<gE256, blk, 0, stream>>>(esrc, edst, cur, ssrc, E);
    k_layer1<<<gN4, blk, 0, stream>>>(offs, ssrc, xw1b, al1sv, al1dv,
                                      b1, W2, a2s, a2d, xw2b, al2sv, al2dv, N);
    k_layer2<<<gN4, blk, 0, stream>>>(offs, ssrc, xw2b, al2sv, al2dv,
                                      b2, Wp, bp, out, N);
}

// Round 4
// 686.257 us; speedup vs baseline: 1.5498x; 1.4579x over previous
//
#include <hip/hip_runtime.h>
#include <hip/hip_bf16.h>
#include <math.h>

#define NEG_SLOPE 0.2f

typedef __hip_bfloat16 bf16;

// ---------------- K1: xw1 = x @ W1 (bf16 out), al1_src/al1_dst ----------------
// block = 256 = 4 waves; each wave computes 4 rows -> 16 rows/block (amortize W1 staging)
__global__ __launch_bounds__(256) void k_feat1(
    const float* __restrict__ x, const float* __restrict__ W1,
    const float* __restrict__ a_src, const float* __restrict__ a_dst,
    bf16* __restrict__ xwb, float* __restrict__ als, float* __restrict__ ald,
    int N)
{
    __shared__ float Wl[128 * 64];   // 32 KB
    int t = threadIdx.x;
    for (int i = t; i < 128 * 64; i += 256) Wl[i] = W1[i];
    __syncthreads();
    int wave = t >> 6, lane = t & 63;
    float as_l = a_src[lane];   // a_src flat [4][16] == [lane]
    float ad_l = a_dst[lane];
    int h = lane >> 4;
    int base = blockIdx.x * 16 + wave * 4;
    for (int r = 0; r < 4; ++r) {
        int row = base + r;
        if (row >= N) return;            // wave-uniform
        float x0 = x[row * 128 + lane];
        float x1 = x[row * 128 + 64 + lane];
        float acc = 0.f;
#pragma unroll
        for (int k = 0; k < 64; ++k)
            acc = fmaf(__shfl(x0, k, 64), Wl[k * 64 + lane], acc);
#pragma unroll
        for (int k = 0; k < 64; ++k)
            acc = fmaf(__shfl(x1, k, 64), Wl[(64 + k) * 64 + lane], acc);
        xwb[row * 64 + lane] = __float2bfloat16(acc);
        float ps = acc * as_l, pd = acc * ad_l;
#pragma unroll
        for (int off = 1; off < 16; off <<= 1) {
            ps += __shfl_xor(ps, off, 64);
            pd += __shfl_xor(pd, off, 64);
        }
        if ((lane & 15) == 0) { als[row * 4 + h] = ps; ald[row * 4 + h] = pd; }
    }
}

// ---------------- CSR build ----------------
__global__ __launch_bounds__(256) void k_fill_deg(int* deg, int N) {
    int i = blockIdx.x * 256 + threadIdx.x;
    if (i < N) deg[i] = 1;  // self-loop
}

__global__ __launch_bounds__(256) void k_deg(const int* __restrict__ dst, int* deg, int E) {
    int i = blockIdx.x * 256 + threadIdx.x;
    if (i < E) atomicAdd(&deg[dst[i]], 1);
}

// ---- 3-phase parallel exclusive scan over deg[N] ----
// Phase A: per-block (256-elem) sums
__global__ __launch_bounds__(256) void k_blocksum(const int* __restrict__ deg, int* __restrict__ partial, int N) {
    __shared__ int red[256];
    int t = threadIdx.x;
    int idx = blockIdx.x * 256 + t;
    red[t] = (idx < N) ? deg[idx] : 0;
    __syncthreads();
    for (int off = 128; off > 0; off >>= 1) {
        if (t < off) red[t] += red[t + off];
        __syncthreads();
    }
    if (t == 0) partial[blockIdx.x] = red[0];
}

// Phase B: single block scans the partials (nb <= 512)
__global__ __launch_bounds__(512) void k_scanpartials(int* __restrict__ partial, int nb) {
    __shared__ int ts[512];
    int t = threadIdx.x;
    int v = (t < nb) ? partial[t] : 0;
    ts[t] = v;
    __syncthreads();
    for (int off = 1; off < 512; off <<= 1) {
        int u = (t >= off) ? ts[t - off] : 0;
        __syncthreads();
        ts[t] += u;
        __syncthreads();
    }
    if (t < nb) partial[t] = ts[t] - v;   // exclusive
}

// Phase C: block-local exclusive scan + base; write offs/cursor/self-loop ssrc
__global__ __launch_bounds__(256) void k_writeoffs(const int* __restrict__ deg, const int* __restrict__ partial,
                                                   int* __restrict__ offs, int* __restrict__ cursor,
                                                   int* __restrict__ ssrc, int N) {
    __shared__ int ts[256];
    int t = threadIdx.x;
    int idx = blockIdx.x * 256 + t;
    int d = (idx < N) ? deg[idx] : 0;
    ts[t] = d;
    __syncthreads();
    for (int off = 1; off < 256; off <<= 1) {
        int u = (t >= off) ? ts[t - off] : 0;
        __syncthreads();
        ts[t] += u;
        __syncthreads();
    }
    int off_ = partial[blockIdx.x] + ts[t] - d;  // exclusive global offset
    if (idx < N) {
        offs[idx] = off_;
        cursor[idx] = off_ + 1;   // slot 0 = self-loop
        ssrc[off_] = idx;
        if (idx == N - 1) offs[N] = off_ + d;
    }
}

__global__ __launch_bounds__(256) void k_scatter(const int* __restrict__ src, const int* __restrict__ dst,
                                                 int* cursor, int* ssrc, int E) {
    int i = blockIdx.x * 256 + threadIdx.x;
    if (i < E) { int pos = atomicAdd(&cursor[dst[i]], 1); ssrc[pos] = src[i]; }
}

// ---------------- K2: layer-1 aggregate (single-pass softmax) -> elu -> @W2 -> al2 ----------------
__global__ __launch_bounds__(256) void k_layer1(
    const int* __restrict__ offs, const int* __restrict__ ssrc,
    const bf16* __restrict__ xwb, const float* __restrict__ alsrc, const float* __restrict__ aldst,
    const float* __restrict__ b1, const float* __restrict__ W2,
    const float* __restrict__ a2s, const float* __restrict__ a2d,
    bf16* __restrict__ xw2b, float* __restrict__ al2s, float* __restrict__ al2d, int N)
{
    __shared__ float Wl[64 * 64];   // 16 KB
    int t = threadIdx.x;
    for (int i = t; i < 64 * 64; i += 256) Wl[i] = W2[i];
    __syncthreads();
    int wave = t >> 6, lane = t & 63;
    int n = blockIdx.x * 4 + wave;
    if (n >= N) return;
    int h = lane >> 4;
    int s0 = offs[n], s1 = offs[n + 1];
    float ad = aldst[n * 4 + h];
    float ssum = 0.f, acc = 0.f;
    int i = s0;
    for (; i + 4 <= s1; i += 4) {
        int sa = ssrc[i], sb = ssrc[i + 1], sc = ssrc[i + 2], sd = ssrc[i + 3];
        float ea = alsrc[sa * 4 + h] + ad;
        float eb = alsrc[sb * 4 + h] + ad;
        float ec = alsrc[sc * 4 + h] + ad;
        float ed = alsrc[sd * 4 + h] + ad;
        float va = __bfloat162float(xwb[sa * 64 + lane]);
        float vb = __bfloat162float(xwb[sb * 64 + lane]);
        float vc = __bfloat162float(xwb[sc * 64 + lane]);
        float vd = __bfloat162float(xwb[sd * 64 + lane]);
        ea = ea > 0.f ? ea : NEG_SLOPE * ea;
        eb = eb > 0.f ? eb : NEG_SLOPE * eb;
        ec = ec > 0.f ? ec : NEG_SLOPE * ec;
        ed = ed > 0.f ? ed : NEG_SLOPE * ed;
        float wa = __expf(fminf(ea, 60.f));
        float wb = __expf(fminf(eb, 60.f));
        float wc = __expf(fminf(ec, 60.f));
        float wd = __expf(fminf(ed, 60.f));
        ssum += (wa + wb) + (wc + wd);
        acc = fmaf(wa, va, acc);
        acc = fmaf(wb, vb, acc);
        acc = fmaf(wc, vc, acc);
        acc = fmaf(wd, vd, acc);
    }
    for (; i < s1; ++i) {
        int s = ssrc[i];
        float e = alsrc[s * 4 + h] + ad;
        float v = __bfloat162float(xwb[s * 64 + lane]);
        e = e > 0.f ? e : NEG_SLOPE * e;
        float w = __expf(fminf(e, 60.f));
        ssum += w;
        acc = fmaf(w, v, acc);
    }
    float hv = acc / ssum + b1[lane];
    hv = hv > 0.f ? hv : expm1f(hv);     // elu
    float o = 0.f;
#pragma unroll 8
    for (int c = 0; c < 64; ++c)
        o = fmaf(__shfl(hv, c, 64), Wl[c * 64 + lane], o);
    xw2b[n * 64 + lane] = __float2bfloat16(o);
    float ps = o * a2s[lane], pd = o * a2d[lane];
#pragma unroll
    for (int off = 1; off < 16; off <<= 1) {
        ps += __shfl_xor(ps, off, 64);
        pd += __shfl_xor(pd, off, 64);
    }
    if ((lane & 15) == 0) { al2s[n * 4 + h] = ps; al2d[n * 4 + h] = pd; }
}

// ---------------- K3: layer-2 aggregate (single-pass) -> elu -> @Wp + bp ----------------
__global__ __launch_bounds__(256) void k_layer2(
    const int* __restrict__ offs, const int* __restrict__ ssrc,
    const bf16* __restrict__ xwb, const float* __restrict__ alsrc, const float* __restrict__ aldst,
    const float* __restrict__ b2v, const float* __restrict__ Wp, const float* __restrict__ bp,
    float* __restrict__ out, int N)
{
    __shared__ float Wl[64 * 64];
    int t = threadIdx.x;
    for (int i = t; i < 64 * 64; i += 256) Wl[i] = Wp[i];
    __syncthreads();
    int wave = t >> 6, lane = t & 63;
    int n = blockIdx.x * 4 + wave;
    if (n >= N) return;
    int h = lane >> 4;
    int s0 = offs[n], s1 = offs[n + 1];
    float ad = aldst[n * 4 + h];
    float ssum = 0.f, acc = 0.f;
    int i = s0;
    for (; i + 4 <= s1; i += 4) {
        int sa = ssrc[i], sb = ssrc[i + 1], sc = ssrc[i + 2], sd = ssrc[i + 3];
        float ea = alsrc[sa * 4 + h] + ad;
        float eb = alsrc[sb * 4 + h] + ad;
        float ec = alsrc[sc * 4 + h] + ad;
        float ed = alsrc[sd * 4 + h] + ad;
        float va = __bfloat162float(xwb[sa * 64 + lane]);
        float vb = __bfloat162float(xwb[sb * 64 + lane]);
        float vc = __bfloat162float(xwb[sc * 64 + lane]);
        float vd = __bfloat162float(xwb[sd * 64 + lane]);
        ea = ea > 0.f ? ea : NEG_SLOPE * ea;
        eb = eb > 0.f ? eb : NEG_SLOPE * eb;
        ec = ec > 0.f ? ec : NEG_SLOPE * ec;
        ed = ed > 0.f ? ed : NEG_SLOPE * ed;
        float wa = __expf(fminf(ea, 60.f));
        float wb = __expf(fminf(eb, 60.f));
        float wc = __expf(fminf(ec, 60.f));
        float wd = __expf(fminf(ed, 60.f));
        ssum += (wa + wb) + (wc + wd);
        acc = fmaf(wa, va, acc);
        acc = fmaf(wb, vb, acc);
        acc = fmaf(wc, vc, acc);
        acc = fmaf(wd, vd, acc);
    }
    for (; i < s1; ++i) {
        int s = ssrc[i];
        float e = alsrc[s * 4 + h] + ad;
        float v = __bfloat162float(xwb[s * 64 + lane]);
        e = e > 0.f ? e : NEG_SLOPE * e;
        float w = __expf(fminf(e, 60.f));
        ssum += w;
        acc = fmaf(w, v, acc);
    }
    float g = acc / ssum + b2v[lane];
    g = g > 0.f ? g : expm1f(g);         // elu
    float o = 0.f;
#pragma unroll 8
    for (int c = 0; c < 64; ++c)
        o = fmaf(__shfl(g, c, 64), Wl[c * 64 + lane], o);
    o += bp[lane];
    out[n * 64 + lane] = o;
}

// ---------------- launch ----------------
extern "C" void kernel_launch(void* const* d_in, const int* in_sizes, int n_in,
                              void* d_out, int out_size, void* d_ws, size_t ws_size,
                              hipStream_t stream) {
    const float* x   = (const float*)d_in[0];
    const int*   ei  = (const int*)d_in[1];
    const float* W1  = (const float*)d_in[2];
    const float* a1s = (const float*)d_in[3];
    const float* a1d = (const float*)d_in[4];
    const float* b1  = (const float*)d_in[5];
    const float* W2  = (const float*)d_in[6];
    const float* a2s = (const float*)d_in[7];
    const float* a2d = (const float*)d_in[8];
    const float* b2  = (const float*)d_in[9];
    const float* Wp  = (const float*)d_in[10];
    const float* bp  = (const float*)d_in[11];
    float* out = (float*)d_out;

    const int N = in_sizes[0] / 128;
    const int E = in_sizes[1] / 2;
    const int Etot = E + N;
    const int* esrc = ei;
    const int* edst = ei + E;

    // workspace layout (~42 MB)
    char* p = (char*)d_ws;
    auto alloc = [&](size_t bytes) {
        char* r = p;
        p += (bytes + 255) & ~(size_t)255;
        return (void*)r;
    };
    bf16*  xw1b  = (bf16*)alloc((size_t)N * 64 * 2);
    bf16*  xw2b  = (bf16*)alloc((size_t)N * 64 * 2);
    float* al1sv = (float*)alloc((size_t)N * 4 * 4);
    float* al1dv = (float*)alloc((size_t)N * 4 * 4);
    float* al2sv = (float*)alloc((size_t)N * 4 * 4);
    float* al2dv = (float*)alloc((size_t)N * 4 * 4);
    int*   deg   = (int*)alloc((size_t)N * 4);
    int*   offs  = (int*)alloc((size_t)(N + 1) * 4);
    int*   cur   = (int*)alloc((size_t)N * 4);
    int*   ssrc  = (int*)alloc((size_t)Etot * 4);
    int*   part  = (int*)alloc((size_t)512 * 4);
    (void)ws_size; (void)n_in; (void)out_size;

    dim3 blk(256);
    int gN256 = (N + 255) / 256;   // = number of scan blocks (<=512 required)
    int gE256 = (E + 255) / 256;
    int gN4   = (N + 3) / 4;
    int gN16  = (N + 15) / 16;

    k_feat1<<<gN16, blk, 0, stream>>>(x, W1, a1s, a1d, xw1b, al1sv, al1dv, N);
    k_fill_deg<<<gN256, blk, 0, stream>>>(deg, N);
    k_deg<<<gE256, blk, 0, stream>>>(edst, deg, E);
    k_blocksum<<<gN256, blk, 0, stream>>>(deg, part, N);
    k_scanpartials<<<1, 512, 0, stream>>>(part, gN256);
    k_writeoffs<<<gN256, blk, 0, stream>>>(deg, part, offs, cur, ssrc, N);
    k_scatter<<<gE256, blk, 0, stream>>>(esrc, edst, cur, ssrc, E);
    k_layer1<<<gN4, blk, 0, stream>>>(offs, ssrc, xw1b, al1sv, al1dv,
                                      b1, W2, a2s, a2d, xw2b, al2sv, al2dv, N);
    k_layer2<<<gN4, blk, 0, stream>>>(offs, ssrc, xw2b, al2sv, al2dv,
                                      b2, Wp, bp, out, N);
}

// Round 5
// 519.734 us; speedup vs baseline: 2.0463x; 1.3204x over previous
//
#include <hip/hip_runtime.h>
#include <hip/hip_bf16.h>
#include <math.h>

#define NEG_SLOPE 0.2f

typedef __bf16 bf16x8 __attribute__((ext_vector_type(8)));
typedef float  f32x4  __attribute__((ext_vector_type(4)));

// manual bf16 <-> f32 bit conversions (RNE), no API dependence
__device__ __forceinline__ unsigned short f2b(float f) {
    union { float f; unsigned u; } c; c.f = f;
    unsigned r = (c.u + 0x7fffu + ((c.u >> 16) & 1u)) >> 16;
    return (unsigned short)r;
}
__device__ __forceinline__ float b2f(unsigned short s) {
    union { unsigned u; float f; } c; c.u = ((unsigned)s) << 16;
    return c.f;
}

// ---------------- K1 (MFMA): xw1 = x @ W1 (bf16 out), al1_src/al1_dst ----------------
// block = 256 = 4 waves; wave computes 16 rows x 64 cols via 16 mfma_f32_16x16x32_bf16
__global__ __launch_bounds__(256) void k_feat1(
    const float* __restrict__ x, const float* __restrict__ W1,
    const float* __restrict__ a_src, const float* __restrict__ a_dst,
    unsigned short* __restrict__ xwb, float* __restrict__ als, float* __restrict__ ald,
    int N)
{
    __shared__ unsigned short WT[64][136];   // W1^T bf16, padded: row stride 272 B (16B-aligned)
    int t = threadIdx.x;
    for (int f = t; f < 128 * 64; f += 256) {
        int k = f >> 6, c = f & 63;
        WT[c][k] = f2b(W1[f]);
    }
    __syncthreads();
    int wave = t >> 6, lane = t & 63;
    int lrow = lane & 15;   // A-row within tile / C-col within coltile
    int lgrp = lane >> 4;   // 0..3
    int r0 = blockIdx.x * 64 + wave * 16;
    if (r0 >= N) return;    // wave fully OOB (wave-uniform)

    // B fragments: bf[ct][ks] = W1[32ks + lgrp*8 + i][16ct + lrow]
    bf16x8 bf[4][4];
#pragma unroll
    for (int ct = 0; ct < 4; ++ct)
#pragma unroll
        for (int ks = 0; ks < 4; ++ks)
            bf[ct][ks] = *(const bf16x8*)&WT[ct * 16 + lrow][ks * 32 + lgrp * 8];

    f32x4 acc[4];
#pragma unroll
    for (int ct = 0; ct < 4; ++ct) acc[ct] = (f32x4){0.f, 0.f, 0.f, 0.f};

    int rowA = r0 + lrow; if (rowA >= N) rowA = N - 1;   // clamp loads
    const float* xp = x + (size_t)rowA * 128 + lgrp * 8;
#pragma unroll
    for (int ks = 0; ks < 4; ++ks) {
        f32x4 v0 = *(const f32x4*)(xp + ks * 32);
        f32x4 v1 = *(const f32x4*)(xp + ks * 32 + 4);
        union { unsigned short s[8]; bf16x8 b; } af;
        af.s[0] = f2b(v0[0]); af.s[1] = f2b(v0[1]); af.s[2] = f2b(v0[2]); af.s[3] = f2b(v0[3]);
        af.s[4] = f2b(v1[0]); af.s[5] = f2b(v1[1]); af.s[6] = f2b(v1[2]); af.s[7] = f2b(v1[3]);
#pragma unroll
        for (int ct = 0; ct < 4; ++ct)
            acc[ct] = __builtin_amdgcn_mfma_f32_16x16x32_bf16(af.b, bf[ct][ks], acc[ct], 0, 0, 0);
    }

    // epilogue: C layout col = 16ct + (lane&15), row = r0 + (lane>>4)*4 + q
    float asv[4], adv[4];
#pragma unroll
    for (int ct = 0; ct < 4; ++ct) { asv[ct] = a_src[ct * 16 + lrow]; adv[ct] = a_dst[ct * 16 + lrow]; }
#pragma unroll
    for (int q = 0; q < 4; ++q) {
        int row = r0 + lgrp * 4 + q;
        bool ok = row < N;
#pragma unroll
        for (int ct = 0; ct < 4; ++ct) {
            float v = acc[ct][q];
            if (ok) xwb[(size_t)row * 64 + ct * 16 + lrow] = f2b(v);
            float ps = v * asv[ct], pd = v * adv[ct];
#pragma unroll
            for (int m = 1; m < 16; m <<= 1) {
                ps += __shfl_xor(ps, m, 64);
                pd += __shfl_xor(pd, m, 64);
            }
            if (ok && lrow == 0) { als[row * 4 + ct] = ps; ald[row * 4 + ct] = pd; }
        }
    }
}

// ---------------- CSR build ----------------
__global__ __launch_bounds__(256) void k_fill_deg(int* deg, int N) {
    int i = blockIdx.x * 256 + threadIdx.x;
    if (i < N) deg[i] = 1;  // self-loop
}

__global__ __launch_bounds__(256) void k_deg(const int* __restrict__ dst, int* deg, int E) {
    int i = blockIdx.x * 256 + threadIdx.x;
    if (i < E) atomicAdd(&deg[dst[i]], 1);
}

// ---- 3-phase parallel exclusive scan over deg[N] ----
__global__ __launch_bounds__(256) void k_blocksum(const int* __restrict__ deg, int* __restrict__ partial, int N) {
    __shared__ int red[256];
    int t = threadIdx.x;
    int idx = blockIdx.x * 256 + t;
    red[t] = (idx < N) ? deg[idx] : 0;
    __syncthreads();
    for (int off = 128; off > 0; off >>= 1) {
        if (t < off) red[t] += red[t + off];
        __syncthreads();
    }
    if (t == 0) partial[blockIdx.x] = red[0];
}

__global__ __launch_bounds__(512) void k_scanpartials(int* __restrict__ partial, int nb) {
    __shared__ int ts[512];
    int t = threadIdx.x;
    int v = (t < nb) ? partial[t] : 0;
    ts[t] = v;
    __syncthreads();
    for (int off = 1; off < 512; off <<= 1) {
        int u = (t >= off) ? ts[t - off] : 0;
        __syncthreads();
        ts[t] += u;
        __syncthreads();
    }
    if (t < nb) partial[t] = ts[t] - v;   // exclusive
}

__global__ __launch_bounds__(256) void k_writeoffs(const int* __restrict__ deg, const int* __restrict__ partial,
                                                   int* __restrict__ offs, int* __restrict__ cursor,
                                                   int* __restrict__ ssrc, int N) {
    __shared__ int ts[256];
    int t = threadIdx.x;
    int idx = blockIdx.x * 256 + t;
    int d = (idx < N) ? deg[idx] : 0;
    ts[t] = d;
    __syncthreads();
    for (int off = 1; off < 256; off <<= 1) {
        int u = (t >= off) ? ts[t - off] : 0;
        __syncthreads();
        ts[t] += u;
        __syncthreads();
    }
    int off_ = partial[blockIdx.x] + ts[t] - d;  // exclusive global offset
    if (idx < N) {
        offs[idx] = off_;
        cursor[idx] = off_ + 1;   // slot 0 = self-loop
        ssrc[off_] = idx;
        if (idx == N - 1) offs[N] = off_ + d;
    }
}

__global__ __launch_bounds__(256) void k_scatter(const int* __restrict__ src, const int* __restrict__ dst,
                                                 int* cursor, int* ssrc, int E) {
    int i = blockIdx.x * 256 + threadIdx.x;
    if (i < E) { int pos = atomicAdd(&cursor[dst[i]], 1); ssrc[pos] = src[i]; }
}

// ---------------- K2: layer-1 aggregate (single-pass softmax) -> elu -> @W2 -> al2 ----------------
__global__ __launch_bounds__(256) void k_layer1(
    const int* __restrict__ offs, const int* __restrict__ ssrc,
    const unsigned short* __restrict__ xwb, const float* __restrict__ alsrc, const float* __restrict__ aldst,
    const float* __restrict__ b1, const float* __restrict__ W2,
    const float* __restrict__ a2s, const float* __restrict__ a2d,
    unsigned short* __restrict__ xw2b, float* __restrict__ al2s, float* __restrict__ al2d, int N)
{
    __shared__ float Wl[64 * 64];   // 16 KB
    int t = threadIdx.x;
    for (int i = t; i < 64 * 64; i += 256) Wl[i] = W2[i];
    __syncthreads();
    int wave = t >> 6, lane = t & 63;
    int n = blockIdx.x * 4 + wave;
    if (n >= N) return;
    int h = lane >> 4;
    int s0 = offs[n], s1 = offs[n + 1];
    float ad = aldst[n * 4 + h];
    float ssum = 0.f, acc = 0.f;
    int i = s0;
    for (; i + 4 <= s1; i += 4) {
        int sa = ssrc[i], sb = ssrc[i + 1], sc = ssrc[i + 2], sd = ssrc[i + 3];
        float ea = alsrc[sa * 4 + h] + ad;
        float eb = alsrc[sb * 4 + h] + ad;
        float ec = alsrc[sc * 4 + h] + ad;
        float ed = alsrc[sd * 4 + h] + ad;
        float va = b2f(xwb[sa * 64 + lane]);
        float vb = b2f(xwb[sb * 64 + lane]);
        float vc = b2f(xwb[sc * 64 + lane]);
        float vd = b2f(xwb[sd * 64 + lane]);
        ea = ea > 0.f ? ea : NEG_SLOPE * ea;
        eb = eb > 0.f ? eb : NEG_SLOPE * eb;
        ec = ec > 0.f ? ec : NEG_SLOPE * ec;
        ed = ed > 0.f ? ed : NEG_SLOPE * ed;
        float wa = __expf(fminf(ea, 60.f));
        float wb = __expf(fminf(eb, 60.f));
        float wc = __expf(fminf(ec, 60.f));
        float wd = __expf(fminf(ed, 60.f));
        ssum += (wa + wb) + (wc + wd);
        acc = fmaf(wa, va, acc);
        acc = fmaf(wb, vb, acc);
        acc = fmaf(wc, vc, acc);
        acc = fmaf(wd, vd, acc);
    }
    for (; i < s1; ++i) {
        int s = ssrc[i];
        float e = alsrc[s * 4 + h] + ad;
        float v = b2f(xwb[s * 64 + lane]);
        e = e > 0.f ? e : NEG_SLOPE * e;
        float w = __expf(fminf(e, 60.f));
        ssum += w;
        acc = fmaf(w, v, acc);
    }
    float hv = acc / ssum + b1[lane];
    hv = hv > 0.f ? hv : expm1f(hv);     // elu
    float o = 0.f;
#pragma unroll 8
    for (int c = 0; c < 64; ++c)
        o = fmaf(__shfl(hv, c, 64), Wl[c * 64 + lane], o);
    xw2b[n * 64 + lane] = f2b(o);
    float ps = o * a2s[lane], pd = o * a2d[lane];
#pragma unroll
    for (int off = 1; off < 16; off <<= 1) {
        ps += __shfl_xor(ps, off, 64);
        pd += __shfl_xor(pd, off, 64);
    }
    if ((lane & 15) == 0) { al2s[n * 4 + h] = ps; al2d[n * 4 + h] = pd; }
}

// ---------------- K3: layer-2 aggregate (single-pass) -> elu -> @Wp + bp ----------------
__global__ __launch_bounds__(256) void k_layer2(
    const int* __restrict__ offs, const int* __restrict__ ssrc,
    const unsigned short* __restrict__ xwb, const float* __restrict__ alsrc, const float* __restrict__ aldst,
    const float* __restrict__ b2v, const float* __restrict__ Wp, const float* __restrict__ bp,
    float* __restrict__ out, int N)
{
    __shared__ float Wl[64 * 64];
    int t = threadIdx.x;
    for (int i = t; i < 64 * 64; i += 256) Wl[i] = Wp[i];
    __syncthreads();
    int wave = t >> 6, lane = t & 63;
    int n = blockIdx.x * 4 + wave;
    if (n >= N) return;
    int h = lane >> 4;
    int s0 = offs[n], s1 = offs[n + 1];
    float ad = aldst[n * 4 + h];
    float ssum = 0.f, acc = 0.f;
    int i = s0;
    for (; i + 4 <= s1; i += 4) {
        int sa = ssrc[i], sb = ssrc[i + 1], sc = ssrc[i + 2], sd = ssrc[i + 3];
        float ea = alsrc[sa * 4 + h] + ad;
        float eb = alsrc[sb * 4 + h] + ad;
        float ec = alsrc[sc * 4 + h] + ad;
        float ed = alsrc[sd * 4 + h] + ad;
        float va = b2f(xwb[sa * 64 + lane]);
        float vb = b2f(xwb[sb * 64 + lane]);
        float vc = b2f(xwb[sc * 64 + lane]);
        float vd = b2f(xwb[sd * 64 + lane]);
        ea = ea > 0.f ? ea : NEG_SLOPE * ea;
        eb = eb > 0.f ? eb : NEG_SLOPE * eb;
        ec = ec > 0.f ? ec : NEG_SLOPE * ec;
        ed = ed > 0.f ? ed : NEG_SLOPE * ed;
        float wa = __expf(fminf(ea, 60.f));
        float wb = __expf(fminf(eb, 60.f));
        float wc = __expf(fminf(ec, 60.f));
        float wd = __expf(fminf(ed, 60.f));
        ssum += (wa + wb) + (wc + wd);
        acc = fmaf(wa, va, acc);
        acc = fmaf(wb, vb, acc);
        acc = fmaf(wc, vc, acc);
        acc = fmaf(wd, vd, acc);
    }
    for (; i < s1; ++i) {
        int s = ssrc[i];
        float e = alsrc[s * 4 + h] + ad;
        float v = b2f(xwb[s * 64 + lane]);
        e = e > 0.f ? e : NEG_SLOPE * e;
        float w = __expf(fminf(e, 60.f));
        ssum += w;
        acc = fmaf(w, v, acc);
    }
    float g = acc / ssum + b2v[lane];
    g = g > 0.f ? g : expm1f(g);         // elu
    float o = 0.f;
#pragma unroll 8
    for (int c = 0; c < 64; ++c)
        o = fmaf(__shfl(g, c, 64), Wl[c * 64 + lane], o);
    o += bp[lane];
    out[n * 64 + lane] = o;
}

// ---------------- launch ----------------
extern "C" void kernel_launch(void* const* d_in, const int* in_sizes, int n_in,
                              void* d_out, int out_size, void* d_ws, size_t ws_size,
                              hipStream_t stream) {
    const float* x   = (const float*)d_in[0];
    const int*   ei  = (const int*)d_in[1];
    const float* W1  = (const float*)d_in[2];
    const float* a1s = (const float*)d_in[3];
    const float* a1d = (const float*)d_in[4];
    const float* b1  = (const float*)d_in[5];
    const float* W2  = (const float*)d_in[6];
    const float* a2s = (const float*)d_in[7];
    const float* a2d = (const float*)d_in[8];
    const float* b2  = (const float*)d_in[9];
    const float* Wp  = (const float*)d_in[10];
    const float* bp  = (const float*)d_in[11];
    float* out = (float*)d_out;

    const int N = in_sizes[0] / 128;
    const int E = in_sizes[1] / 2;
    const int Etot = E + N;
    const int* esrc = ei;
    const int* edst = ei + E;

    // workspace layout (~42 MB)
    char* p = (char*)d_ws;
    auto alloc = [&](size_t bytes) {
        char* r = p;
        p += (bytes + 255) & ~(size_t)255;
        return (void*)r;
    };
    unsigned short* xw1b = (unsigned short*)alloc((size_t)N * 64 * 2);
    unsigned short* xw2b = (unsigned short*)alloc((size_t)N * 64 * 2);
    float* al1sv = (float*)alloc((size_t)N * 4 * 4);
    float* al1dv = (float*)alloc((size_t)N * 4 * 4);
    float* al2sv = (float*)alloc((size_t)N * 4 * 4);
    float* al2dv = (float*)alloc((size_t)N * 4 * 4);
    int*   deg   = (int*)alloc((size_t)N * 4);
    int*   offs  = (int*)alloc((size_t)(N + 1) * 4);
    int*   cur   = (int*)alloc((size_t)N * 4);
    int*   ssrc  = (int*)alloc((size_t)Etot * 4);
    int*   part  = (int*)alloc((size_t)512 * 4);
    (void)ws_size; (void)n_in; (void)out_size;

    dim3 blk(256);
    int gN256 = (N + 255) / 256;   // scan blocks (<=512)
    int gE256 = (E + 255) / 256;
    int gN4   = (N + 3) / 4;
    int gN64  = (N + 63) / 64;

    k_feat1<<<gN64, blk, 0, stream>>>(x, W1, a1s, a1d, xw1b, al1sv, al1dv, N);
    k_fill_deg<<<gN256, blk, 0, stream>>>(deg, N);
    k_deg<<<gE256, blk, 0, stream>>>(edst, deg, E);
    k_blocksum<<<gN256, blk, 0, stream>>>(deg, part, N);
    k_scanpartials<<<1, 512, 0, stream>>>(part, gN256);
    k_writeoffs<<<gN256, blk, 0, stream>>>(deg, part, offs, cur, ssrc, N);
    k_scatter<<<gE256, blk, 0, stream>>>(esrc, edst, cur, ssrc, E);
    k_layer1<<<gN4, blk, 0, stream>>>(offs, ssrc, xw1b, al1sv, al1dv,
                                      b1, W2, a2s, a2d, xw2b, al2sv, al2dv, N);
    k_layer2<<<gN4, blk, 0, stream>>>(offs, ssrc, xw2b, al2sv, al2dv,
                                      b2, Wp, bp, out, N);
}

// Round 6
// 407.374 us; speedup vs baseline: 2.6107x; 1.2758x over previous
//
#include <hip/hip_runtime.h>
#include <hip/hip_bf16.h>
#include <math.h>

#define NEG_SLOPE 0.2f

typedef __bf16 bf16x8 __attribute__((ext_vector_type(8)));
typedef float  f32x4  __attribute__((ext_vector_type(4)));

// manual bf16 <-> f32 bit conversions (RNE), no API dependence
__device__ __forceinline__ unsigned short f2b(float f) {
    union { float f; unsigned u; } c; c.f = f;
    unsigned r = (c.u + 0x7fffu + ((c.u >> 16) & 1u)) >> 16;
    return (unsigned short)r;
}
__device__ __forceinline__ float b2f(unsigned short s) {
    union { unsigned u; float f; } c; c.u = ((unsigned)s) << 16;
    return c.f;
}

// ---------------- K1 (MFMA): xw1 = x @ W1 (bf16 out), al1_src/al1_dst; also deg=1 init ----------------
// block = 256 = 4 waves; wave computes 16 rows x 64 cols via 16 mfma_f32_16x16x32_bf16
__global__ __launch_bounds__(256) void k_feat1(
    const float* __restrict__ x, const float* __restrict__ W1,
    const float* __restrict__ a_src, const float* __restrict__ a_dst,
    unsigned short* __restrict__ xwb, float* __restrict__ als, float* __restrict__ ald,
    int* __restrict__ deg, int N)
{
    int t = threadIdx.x;
    int gid = blockIdx.x * 256 + t;
    if (gid < N) deg[gid] = 1;            // fused self-loop degree init

    __shared__ unsigned short WT[64][136];   // W1^T bf16, padded row stride 272 B
    for (int f = t; f < 128 * 64; f += 256) {
        int k = f >> 6, c = f & 63;
        WT[c][k] = f2b(W1[f]);
    }
    __syncthreads();
    int wave = t >> 6, lane = t & 63;
    int lrow = lane & 15;   // A-row within tile / C-col within coltile
    int lgrp = lane >> 4;   // 0..3
    int r0 = blockIdx.x * 64 + wave * 16;
    if (r0 >= N) return;    // wave-uniform

    bf16x8 bf[4][4];
#pragma unroll
    for (int ct = 0; ct < 4; ++ct)
#pragma unroll
        for (int ks = 0; ks < 4; ++ks)
            bf[ct][ks] = *(const bf16x8*)&WT[ct * 16 + lrow][ks * 32 + lgrp * 8];

    f32x4 acc[4];
#pragma unroll
    for (int ct = 0; ct < 4; ++ct) acc[ct] = (f32x4){0.f, 0.f, 0.f, 0.f};

    int rowA = r0 + lrow; if (rowA >= N) rowA = N - 1;   // clamp loads
    const float* xp = x + (size_t)rowA * 128 + lgrp * 8;
#pragma unroll
    for (int ks = 0; ks < 4; ++ks) {
        f32x4 v0 = *(const f32x4*)(xp + ks * 32);
        f32x4 v1 = *(const f32x4*)(xp + ks * 32 + 4);
        union { unsigned short s[8]; bf16x8 b; } af;
        af.s[0] = f2b(v0[0]); af.s[1] = f2b(v0[1]); af.s[2] = f2b(v0[2]); af.s[3] = f2b(v0[3]);
        af.s[4] = f2b(v1[0]); af.s[5] = f2b(v1[1]); af.s[6] = f2b(v1[2]); af.s[7] = f2b(v1[3]);
#pragma unroll
        for (int ct = 0; ct < 4; ++ct)
            acc[ct] = __builtin_amdgcn_mfma_f32_16x16x32_bf16(af.b, bf[ct][ks], acc[ct], 0, 0, 0);
    }

    float asv[4], adv[4];
#pragma unroll
    for (int ct = 0; ct < 4; ++ct) { asv[ct] = a_src[ct * 16 + lrow]; adv[ct] = a_dst[ct * 16 + lrow]; }
#pragma unroll
    for (int q = 0; q < 4; ++q) {
        int row = r0 + lgrp * 4 + q;
        bool ok = row < N;
#pragma unroll
        for (int ct = 0; ct < 4; ++ct) {
            float v = acc[ct][q];
            if (ok) xwb[(size_t)row * 64 + ct * 16 + lrow] = f2b(v);
            float ps = v * asv[ct], pd = v * adv[ct];
#pragma unroll
            for (int m = 1; m < 16; m <<= 1) {
                ps += __shfl_xor(ps, m, 64);
                pd += __shfl_xor(pd, m, 64);
            }
            if (ok && lrow == 0) { als[row * 4 + ct] = ps; ald[row * 4 + ct] = pd; }
        }
    }
}

// ---------------- K-feat (MFMA, K=64): xw = h @ W + logits ----------------
__global__ __launch_bounds__(256) void k_feat2(
    const unsigned short* __restrict__ hb, const float* __restrict__ W,
    const float* __restrict__ a_src, const float* __restrict__ a_dst,
    unsigned short* __restrict__ xwb, float* __restrict__ als, float* __restrict__ ald, int N)
{
    __shared__ unsigned short WT[64][72];   // W^T bf16, padded row stride 144 B
    int t = threadIdx.x;
    for (int f = t; f < 64 * 64; f += 256) {
        int k = f >> 6, c = f & 63;
        WT[c][k] = f2b(W[f]);
    }
    __syncthreads();
    int wave = t >> 6, lane = t & 63;
    int lrow = lane & 15, lgrp = lane >> 4;
    int r0 = blockIdx.x * 64 + wave * 16;
    if (r0 >= N) return;

    bf16x8 bf[4][2];
#pragma unroll
    for (int ct = 0; ct < 4; ++ct)
#pragma unroll
        for (int ks = 0; ks < 2; ++ks)
            bf[ct][ks] = *(const bf16x8*)&WT[ct * 16 + lrow][ks * 32 + lgrp * 8];

    f32x4 acc[4];
#pragma unroll
    for (int ct = 0; ct < 4; ++ct) acc[ct] = (f32x4){0.f, 0.f, 0.f, 0.f};

    int rowA = r0 + lrow; if (rowA >= N) rowA = N - 1;
    const unsigned short* hp = hb + (size_t)rowA * 64 + lgrp * 8;
#pragma unroll
    for (int ks = 0; ks < 2; ++ks) {
        bf16x8 af = *(const bf16x8*)(hp + ks * 32);
#pragma unroll
        for (int ct = 0; ct < 4; ++ct)
            acc[ct] = __builtin_amdgcn_mfma_f32_16x16x32_bf16(af, bf[ct][ks], acc[ct], 0, 0, 0);
    }

    float asv[4], adv[4];
#pragma unroll
    for (int ct = 0; ct < 4; ++ct) { asv[ct] = a_src[ct * 16 + lrow]; adv[ct] = a_dst[ct * 16 + lrow]; }
#pragma unroll
    for (int q = 0; q < 4; ++q) {
        int row = r0 + lgrp * 4 + q;
        bool ok = row < N;
#pragma unroll
        for (int ct = 0; ct < 4; ++ct) {
            float v = acc[ct][q];
            if (ok) xwb[(size_t)row * 64 + ct * 16 + lrow] = f2b(v);
            float ps = v * asv[ct], pd = v * adv[ct];
#pragma unroll
            for (int m = 1; m < 16; m <<= 1) {
                ps += __shfl_xor(ps, m, 64);
                pd += __shfl_xor(pd, m, 64);
            }
            if (ok && lrow == 0) { als[row * 4 + ct] = ps; ald[row * 4 + ct] = pd; }
        }
    }
}

// ---------------- K-proj (MFMA, K=64): out = g @ Wp + bp (f32) ----------------
__global__ __launch_bounds__(256) void k_proj(
    const unsigned short* __restrict__ gb, const float* __restrict__ Wp,
    const float* __restrict__ bp, float* __restrict__ out, int N)
{
    __shared__ unsigned short WT[64][72];
    int t = threadIdx.x;
    for (int f = t; f < 64 * 64; f += 256) {
        int k = f >> 6, c = f & 63;
        WT[c][k] = f2b(Wp[f]);
    }
    __syncthreads();
    int wave = t >> 6, lane = t & 63;
    int lrow = lane & 15, lgrp = lane >> 4;
    int r0 = blockIdx.x * 64 + wave * 16;
    if (r0 >= N) return;

    bf16x8 bf[4][2];
#pragma unroll
    for (int ct = 0; ct < 4; ++ct)
#pragma unroll
        for (int ks = 0; ks < 2; ++ks)
            bf[ct][ks] = *(const bf16x8*)&WT[ct * 16 + lrow][ks * 32 + lgrp * 8];

    f32x4 acc[4];
#pragma unroll
    for (int ct = 0; ct < 4; ++ct) acc[ct] = (f32x4){0.f, 0.f, 0.f, 0.f};

    int rowA = r0 + lrow; if (rowA >= N) rowA = N - 1;
    const unsigned short* gp = gb + (size_t)rowA * 64 + lgrp * 8;
#pragma unroll
    for (int ks = 0; ks < 2; ++ks) {
        bf16x8 af = *(const bf16x8*)(gp + ks * 32);
#pragma unroll
        for (int ct = 0; ct < 4; ++ct)
            acc[ct] = __builtin_amdgcn_mfma_f32_16x16x32_bf16(af, bf[ct][ks], acc[ct], 0, 0, 0);
    }

    float bpv[4];
#pragma unroll
    for (int ct = 0; ct < 4; ++ct) bpv[ct] = bp[ct * 16 + lrow];
#pragma unroll
    for (int q = 0; q < 4; ++q) {
        int row = r0 + lgrp * 4 + q;
        if (row >= N) break;
#pragma unroll
        for (int ct = 0; ct < 4; ++ct)
            out[(size_t)row * 64 + ct * 16 + lrow] = acc[ct][q] + bpv[ct];
    }
}

// ---------------- CSR build ----------------
__global__ __launch_bounds__(256) void k_deg(const int* __restrict__ dst, int* deg, int E) {
    int i = blockIdx.x * 256 + threadIdx.x;
    if (i < E) atomicAdd(&deg[dst[i]], 1);
}

__global__ __launch_bounds__(256) void k_blocksum(const int* __restrict__ deg, int* __restrict__ partial, int N) {
    __shared__ int red[256];
    int t = threadIdx.x;
    int idx = blockIdx.x * 256 + t;
    red[t] = (idx < N) ? deg[idx] : 0;
    __syncthreads();
    for (int off = 128; off > 0; off >>= 1) {
        if (t < off) red[t] += red[t + off];
        __syncthreads();
    }
    if (t == 0) partial[blockIdx.x] = red[0];
}

__global__ __launch_bounds__(512) void k_scanpartials(int* __restrict__ partial, int nb) {
    __shared__ int ts[512];
    int t = threadIdx.x;
    int v = (t < nb) ? partial[t] : 0;
    ts[t] = v;
    __syncthreads();
    for (int off = 1; off < 512; off <<= 1) {
        int u = (t >= off) ? ts[t - off] : 0;
        __syncthreads();
        ts[t] += u;
        __syncthreads();
    }
    if (t < nb) partial[t] = ts[t] - v;   // exclusive
}

__global__ __launch_bounds__(256) void k_writeoffs(const int* __restrict__ deg, const int* __restrict__ partial,
                                                   int* __restrict__ offs, int* __restrict__ cursor,
                                                   int* __restrict__ ssrc, int N) {
    __shared__ int ts[256];
    int t = threadIdx.x;
    int idx = blockIdx.x * 256 + t;
    int d = (idx < N) ? deg[idx] : 0;
    ts[t] = d;
    __syncthreads();
    for (int off = 1; off < 256; off <<= 1) {
        int u = (t >= off) ? ts[t - off] : 0;
        __syncthreads();
        ts[t] += u;
        __syncthreads();
    }
    int off_ = partial[blockIdx.x] + ts[t] - d;  // exclusive global offset
    if (idx < N) {
        offs[idx] = off_;
        cursor[idx] = off_ + 1;   // slot 0 = self-loop
        ssrc[off_] = idx;
        if (idx == N - 1) offs[N] = off_ + d;
    }
}

__global__ __launch_bounds__(256) void k_scatter(const int* __restrict__ src, const int* __restrict__ dst,
                                                 int* cursor, int* ssrc, int E) {
    int i = blockIdx.x * 256 + threadIdx.x;
    if (i < E) { int pos = atomicAdd(&cursor[dst[i]], 1); ssrc[pos] = src[i]; }
}

// ---------------- K-agg: segment softmax aggregate + bias + elu -> bf16 h ----------------
__global__ __launch_bounds__(256) void k_aggregate(
    const int* __restrict__ offs, const int* __restrict__ ssrc,
    const unsigned short* __restrict__ xwb, const float* __restrict__ alsrc,
    const float* __restrict__ aldst, const float* __restrict__ bias,
    unsigned short* __restrict__ hout, int N)
{
    int t = threadIdx.x;
    int wave = t >> 6, lane = t & 63;
    int n = blockIdx.x * 4 + wave;
    if (n >= N) return;
    int h = lane >> 4;
    int s0 = offs[n], s1 = offs[n + 1];
    float ad = aldst[n * 4 + h];
    float ssum = 0.f, acc = 0.f;
    int i = s0;
    for (; i + 4 <= s1; i += 4) {
        int sa = ssrc[i], sb = ssrc[i + 1], sc = ssrc[i + 2], sd = ssrc[i + 3];
        float ea = alsrc[sa * 4 + h] + ad;
        float eb = alsrc[sb * 4 + h] + ad;
        float ec = alsrc[sc * 4 + h] + ad;
        float ed = alsrc[sd * 4 + h] + ad;
        float va = b2f(xwb[sa * 64 + lane]);
        float vb = b2f(xwb[sb * 64 + lane]);
        float vc = b2f(xwb[sc * 64 + lane]);
        float vd = b2f(xwb[sd * 64 + lane]);
        ea = ea > 0.f ? ea : NEG_SLOPE * ea;
        eb = eb > 0.f ? eb : NEG_SLOPE * eb;
        ec = ec > 0.f ? ec : NEG_SLOPE * ec;
        ed = ed > 0.f ? ed : NEG_SLOPE * ed;
        float wa = __expf(fminf(ea, 60.f));
        float wb = __expf(fminf(eb, 60.f));
        float wc = __expf(fminf(ec, 60.f));
        float wd = __expf(fminf(ed, 60.f));
        ssum += (wa + wb) + (wc + wd);
        acc = fmaf(wa, va, acc);
        acc = fmaf(wb, vb, acc);
        acc = fmaf(wc, vc, acc);
        acc = fmaf(wd, vd, acc);
    }
    for (; i < s1; ++i) {
        int s = ssrc[i];
        float e = alsrc[s * 4 + h] + ad;
        float v = b2f(xwb[s * 64 + lane]);
        e = e > 0.f ? e : NEG_SLOPE * e;
        float w = __expf(fminf(e, 60.f));
        ssum += w;
        acc = fmaf(w, v, acc);
    }
    float hv = acc / ssum + bias[lane];
    hv = hv > 0.f ? hv : expm1f(hv);     // elu
    hout[(size_t)n * 64 + lane] = f2b(hv);
}

// ---------------- launch ----------------
extern "C" void kernel_launch(void* const* d_in, const int* in_sizes, int n_in,
                              void* d_out, int out_size, void* d_ws, size_t ws_size,
                              hipStream_t stream) {
    const float* x   = (const float*)d_in[0];
    const int*   ei  = (const int*)d_in[1];
    const float* W1  = (const float*)d_in[2];
    const float* a1s = (const float*)d_in[3];
    const float* a1d = (const float*)d_in[4];
    const float* b1  = (const float*)d_in[5];
    const float* W2  = (const float*)d_in[6];
    const float* a2s = (const float*)d_in[7];
    const float* a2d = (const float*)d_in[8];
    const float* b2  = (const float*)d_in[9];
    const float* Wp  = (const float*)d_in[10];
    const float* bp  = (const float*)d_in[11];
    float* out = (float*)d_out;

    const int N = in_sizes[0] / 128;
    const int E = in_sizes[1] / 2;
    const int Etot = E + N;
    const int* esrc = ei;
    const int* edst = ei + E;

    // workspace layout
    char* p = (char*)d_ws;
    auto alloc = [&](size_t bytes) {
        char* r = p;
        p += (bytes + 255) & ~(size_t)255;
        return (void*)r;
    };
    unsigned short* xw1b = (unsigned short*)alloc((size_t)N * 64 * 2);
    unsigned short* xw2b = (unsigned short*)alloc((size_t)N * 64 * 2);
    unsigned short* h1b  = (unsigned short*)alloc((size_t)N * 64 * 2);
    unsigned short* h2b  = (unsigned short*)alloc((size_t)N * 64 * 2);
    float* al1sv = (float*)alloc((size_t)N * 4 * 4);
    float* al1dv = (float*)alloc((size_t)N * 4 * 4);
    float* al2sv = (float*)alloc((size_t)N * 4 * 4);
    float* al2dv = (float*)alloc((size_t)N * 4 * 4);
    int*   deg   = (int*)alloc((size_t)N * 4);
    int*   offs  = (int*)alloc((size_t)(N + 1) * 4);
    int*   cur   = (int*)alloc((size_t)N * 4);
    int*   ssrc  = (int*)alloc((size_t)Etot * 4);
    int*   part  = (int*)alloc((size_t)512 * 4);
    (void)ws_size; (void)n_in; (void)out_size;

    dim3 blk(256);
    int gN256 = (N + 255) / 256;   // scan blocks (<=512)
    int gE256 = (E + 255) / 256;
    int gN4   = (N + 3) / 4;
    int gN64  = (N + 63) / 64;

    k_feat1<<<gN64, blk, 0, stream>>>(x, W1, a1s, a1d, xw1b, al1sv, al1dv, deg, N);
    k_deg<<<gE256, blk, 0, stream>>>(edst, deg, E);
    k_blocksum<<<gN256, blk, 0, stream>>>(deg, part, N);
    k_scanpartials<<<1, 512, 0, stream>>>(part, gN256);
    k_writeoffs<<<gN256, blk, 0, stream>>>(deg, part, offs, cur, ssrc, N);
    k_scatter<<<gE256, blk, 0, stream>>>(esrc, edst, cur, ssrc, E);
    k_aggregate<<<gN4, blk, 0, stream>>>(offs, ssrc, xw1b, al1sv, al1dv, b1, h1b, N);
    k_feat2<<<gN64, blk, 0, stream>>>(h1b, W2, a2s, a2d, xw2b, al2sv, al2dv, N);
    k_aggregate<<<gN4, blk, 0, stream>>>(offs, ssrc, xw2b, al2sv, al2dv, b2, h2b, N);
    k_proj<<<gN64, blk, 0, stream>>>(h2b, Wp, bp, out, N);
}